// Round 1
// baseline (267.527 us; speedup 1.0000x reference)
//
#include <hip/hip_runtime.h>

#define HH 80
#define WW 80
#define IMG (HH * WW)            // 6400
#define NV ((HH - 1) * WW)       // 6320 vertical edge slots
#define NHZ (HH * (WW - 1))      // 6320 horizontal edge slots
#define NPTS (NV + NHZ)          // 12640 per image
#define NPIX (2 * IMG)           // 12800
#define BIGF 1.0e10f
#define INVC 1.0e7f              // coordinate for invalid points
#define EPSF 1e-8f
#define NSLICE 8
#define SLICELEN (NPTS / NSLICE) // 1580
#define CHUNKS ((NPTS + 255) / 256) // 50

// ---------------------------------------------------------------- reductions
__device__ __forceinline__ float block_reduce_sum(float v, float* sbuf) {
#pragma unroll
  for (int o = 32; o > 0; o >>= 1) v += __shfl_down(v, o, 64);
  int lane = threadIdx.x & 63, wid = threadIdx.x >> 6;
  if (lane == 0) sbuf[wid] = v;
  __syncthreads();
  if (threadIdx.x == 0) {
    v = sbuf[0];
    for (int w = 1; w < 4; ++w) v += sbuf[w];
  }
  return v;
}

// ---------------------------------------------------------------- pixel loss
__global__ void k_pixel(const float* __restrict__ pred,
                        const float* __restrict__ gt, float* acc) {
  __shared__ float sbuf[4];
  float s = 0.f;
  for (int i = threadIdx.x; i < NPIX; i += 256) s += fabsf(pred[i] - gt[i]);
  s = block_reduce_sum(s, sbuf);
  if (threadIdx.x == 0) acc[0] = s / (float)NPIX;
}

// ------------------------------------------------------- zero-crossing points
// set 0: pred b=0, set 1: pred b=1, set 2: gt b=0, set 3: gt b=1
__global__ void k_extract(const float* __restrict__ pred,
                          const float* __restrict__ gt,
                          float2* __restrict__ pts, float* __restrict__ minarr) {
  int set = blockIdx.y;
  int idx = blockIdx.x * 256 + threadIdx.x;
  if (idx >= NPTS) return;
  const float* s = (set < 2 ? pred : gt) + (set & 1) * IMG;

  float r, c;
  bool valid;
  if (idx < NV) {  // vertical pair (i,j)-(i+1,j)
    int i = idx / WW, j = idx - i * WW;
    float v1 = s[i * WW + j];
    float v2 = s[(i + 1) * WW + j];
    c = (float)j;
    if (v1 == 0.f)      { r = (float)i;        valid = true; }
    else if (v2 == 0.f) { r = (float)i + 1.f;  valid = true; }
    else {
      float alpha = fabsf(v1) / (fabsf(v1) + fabsf(v2) + EPSF);
      r = (float)i + alpha;
      valid = (v1 * v2 < 0.f);
    }
  } else {          // horizontal pair (i,j)-(i,j+1)
    int t = idx - NV;
    int i = t / (WW - 1), j = t - i * (WW - 1);
    float h1 = s[i * WW + j];
    float h2 = s[i * WW + j + 1];
    r = (float)i;
    if (h1 == 0.f)      { c = (float)j;        valid = true; }
    else if (h2 == 0.f) { c = (float)j + 1.f;  valid = true; }
    else {
      float beta = fabsf(h1) / (fabsf(h1) + fabsf(h2) + EPSF);
      c = (float)j + beta;
      valid = (h1 * h2 < 0.f);
    }
  }
  pts[set * NPTS + idx] = valid ? make_float2(r, c) : make_float2(INVC, INVC);
  minarr[set * NPTS + idx] = BIGF;  // init for the min pass
}

// ------------------------------------------------------------- chamfer mins
// dir 0: A=set0 vs B=set2;  dir 1: A=set2 vs B=set0
// dir 2: A=set1 vs B=set3;  dir 3: A=set3 vs B=set1
__global__ void k_min(const float2* __restrict__ pts, float* __restrict__ minarr) {
  __shared__ float2 tile[256];
  int dir = blockIdx.z;
  int Aset = ((dir & 1) << 1) | (dir >> 1);
  int Bset = Aset ^ 2;

  int a = blockIdx.x * 256 + threadIdx.x;
  bool activeA = (a < NPTS);
  float2 p = activeA ? pts[Aset * NPTS + a] : make_float2(0.f, 0.f);

  int b0 = blockIdx.y * SLICELEN;
  int b1 = b0 + SLICELEN;

  float dmin2 = 3.0e38f;
  for (int base = b0; base < b1; base += 256) {
    int bi = base + threadIdx.x;
    tile[threadIdx.x] = (bi < b1) ? pts[Bset * NPTS + bi]
                                  : make_float2(INVC, INVC);
    __syncthreads();
    int n = min(256, b1 - base);
#pragma unroll 4
    for (int k = 0; k < n; ++k) {
      float dx = p.x - tile[k].x;
      float dy = p.y - tile[k].y;
      float d2 = fmaf(dx, dx, dy * dy);
      dmin2 = fminf(dmin2, d2);
    }
    __syncthreads();
  }
  if (activeA) {
    float dmin = sqrtf(dmin2);
    // non-negative floats order-preserve as uint bit patterns; exact & deterministic
    atomicMin((unsigned int*)&minarr[Aset * NPTS + a], __float_as_uint(dmin));
  }
}

// --------------------------------------------------------------- per-set sums
__global__ void k_reduce(const float2* __restrict__ pts,
                         const float* __restrict__ minarr,
                         float* acc, int* cnt) {
  __shared__ float sbuf[4];
  int set = blockIdx.x;
  float s = 0.f, c = 0.f;
  for (int i = threadIdx.x; i < NPTS; i += 256) {
    float2 p = pts[set * NPTS + i];
    if (p.x < 1.0e6f) { s += minarr[set * NPTS + i]; c += 1.f; }
  }
  s = block_reduce_sum(s, sbuf);
  __syncthreads();
  c = block_reduce_sum(c, sbuf);
  if (threadIdx.x == 0) { acc[1 + set] = s; cnt[set] = (int)c; }
}

// ---------------------------------------------------------------- final combine
__global__ void k_final(const float* __restrict__ acc, const int* __restrict__ cnt,
                        float* __restrict__ out) {
  // chamfer_b = -sum_pred/np + sum_gt/ng
  float ch0 = -acc[1] / fmaxf((float)cnt[0], 1.f) + acc[3] / fmaxf((float)cnt[2], 1.f);
  float ch1 = -acc[2] / fmaxf((float)cnt[1], 1.f) + acc[4] / fmaxf((float)cnt[3], 1.f);
  out[0] = acc[0];               // PIXEL_W * pixel_loss, PIXEL_W = 1
  out[1] = 0.5f * (ch0 + ch1);   // mean over the 2 batches
}

extern "C" void kernel_launch(void* const* d_in, const int* in_sizes, int n_in,
                              void* d_out, int out_size, void* d_ws, size_t ws_size,
                              hipStream_t stream) {
  const float* pred = (const float*)d_in[0];
  const float* gt   = (const float*)d_in[1];
  float* out = (float*)d_out;

  // ws layout: [0..255] scalars | 4*NPTS float2 points | 4*NPTS float mins
  float* acc = (float*)d_ws;               // acc[0]=pixel, acc[1..4]=per-set sums
  int*   cnt = (int*)d_ws + 8;             // cnt[0..3]
  float2* pts = (float2*)((char*)d_ws + 256);
  float* minarr = (float*)((char*)d_ws + 256 + sizeof(float2) * 4 * NPTS);

  k_pixel<<<1, 256, 0, stream>>>(pred, gt, acc);
  k_extract<<<dim3(CHUNKS, 4), 256, 0, stream>>>(pred, gt, pts, minarr);
  k_min<<<dim3(CHUNKS, NSLICE, 4), 256, 0, stream>>>(pts, minarr);
  k_reduce<<<4, 256, 0, stream>>>(pts, minarr, acc, cnt);
  k_final<<<1, 1, 0, stream>>>(acc, cnt, out);
}

// Round 2
// 97.504 us; speedup vs baseline: 2.7437x; 2.7437x over previous
//
#include <hip/hip_runtime.h>

#define HH 80
#define WW 80
#define IMG (HH * WW)            // 6400
#define NV ((HH - 1) * WW)       // 6320 vertical edge slots
#define NHZ (HH * (WW - 1))      // 6320 horizontal edge slots
#define NPTS (NV + NHZ)          // 12640 per image
#define NPIX (2 * IMG)           // 12800
#define BIGF 1.0e10f
#define INVC 1.0e7f              // coordinate for invalid points
#define EPSF 1e-8f

#define APT 8                    // A points per thread
#define BLK 128                  // threads per k_min block (2 waves)
#define NSLICE 20
#define SLICELEN (NPTS / NSLICE) // 632 (even, exact)
#define ABLOCKS ((NPTS + BLK * APT - 1) / (BLK * APT)) // 13
#define EXCHUNKS ((NPTS + 255) / 256) // 50

// ---------------------------------------------------------------- reductions
__device__ __forceinline__ float block_reduce_sum(float v, float* sbuf) {
#pragma unroll
  for (int o = 32; o > 0; o >>= 1) v += __shfl_down(v, o, 64);
  int lane = threadIdx.x & 63, wid = threadIdx.x >> 6;
  if (lane == 0) sbuf[wid] = v;
  __syncthreads();
  if (threadIdx.x == 0) {
    v = sbuf[0];
    for (int w = 1; w < 4; ++w) v += sbuf[w];
  }
  return v;
}

// ---------------------------------------------------------------- pixel loss
__global__ void k_pixel(const float* __restrict__ pred,
                        const float* __restrict__ gt, float* acc) {
  __shared__ float sbuf[4];
  float s = 0.f;
  for (int i = threadIdx.x; i < NPIX; i += 256) s += fabsf(pred[i] - gt[i]);
  s = block_reduce_sum(s, sbuf);
  if (threadIdx.x == 0) acc[0] = s / (float)NPIX;
}

// ------------------------------------------------------- zero-crossing points
// set 0: pred b=0, set 1: pred b=1, set 2: gt b=0, set 3: gt b=1
__global__ void k_extract(const float* __restrict__ pred,
                          const float* __restrict__ gt,
                          float2* __restrict__ pts, float* __restrict__ minarr) {
  int set = blockIdx.y;
  int idx = blockIdx.x * 256 + threadIdx.x;
  if (idx >= NPTS) return;
  const float* s = (set < 2 ? pred : gt) + (set & 1) * IMG;

  float r, c;
  bool valid;
  if (idx < NV) {  // vertical pair (i,j)-(i+1,j)
    int i = idx / WW, j = idx - i * WW;
    float v1 = s[i * WW + j];
    float v2 = s[(i + 1) * WW + j];
    c = (float)j;
    if (v1 == 0.f)      { r = (float)i;        valid = true; }
    else if (v2 == 0.f) { r = (float)i + 1.f;  valid = true; }
    else {
      float alpha = fabsf(v1) / (fabsf(v1) + fabsf(v2) + EPSF);
      r = (float)i + alpha;
      valid = (v1 * v2 < 0.f);
    }
  } else {          // horizontal pair (i,j)-(i,j+1)
    int t = idx - NV;
    int i = t / (WW - 1), j = t - i * (WW - 1);
    float h1 = s[i * WW + j];
    float h2 = s[i * WW + j + 1];
    r = (float)i;
    if (h1 == 0.f)      { c = (float)j;        valid = true; }
    else if (h2 == 0.f) { c = (float)j + 1.f;  valid = true; }
    else {
      float beta = fabsf(h1) / (fabsf(h1) + fabsf(h2) + EPSF);
      c = (float)j + beta;
      valid = (h1 * h2 < 0.f);
    }
  }
  pts[set * NPTS + idx] = valid ? make_float2(r, c) : make_float2(INVC, INVC);
  minarr[set * NPTS + idx] = BIGF;  // init for the min pass
}

// ------------------------------------------------------------- chamfer mins
// dir 0: A=set0 vs B=set2;  dir 1: A=set2 vs B=set0
// dir 2: A=set1 vs B=set3;  dir 3: A=set3 vs B=set1
// min over b of (q2 - 2px*qx - 2py*qy), then + p2, clamp, sqrt (all monotone).
__global__ void k_min(const float2* __restrict__ pts, float* __restrict__ minarr) {
  __shared__ float4 tile[SLICELEN];
  int dir = blockIdx.z;
  int Aset = ((dir & 1) << 1) | (dir >> 1);
  int Bset = Aset ^ 2;
  int b0 = blockIdx.y * SLICELEN;

  // stage B slice once; precompute q2 = qx^2 + qy^2
  for (int i = threadIdx.x; i < SLICELEN; i += BLK) {
    float2 q = pts[Bset * NPTS + b0 + i];
    tile[i] = make_float4(q.x, q.y, fmaf(q.x, q.x, q.y * q.y), 0.f);
  }
  __syncthreads();

  int abase = blockIdx.x * (BLK * APT) + threadIdx.x;
  float nx[APT], ny[APT], p2[APT], m[APT];
#pragma unroll
  for (int i = 0; i < APT; ++i) {
    int a = abase + i * BLK;
    float2 p = (a < NPTS) ? pts[Aset * NPTS + a] : make_float2(0.f, 0.f);
    nx[i] = -2.f * p.x;
    ny[i] = -2.f * p.y;
    p2[i] = fmaf(p.x, p.x, p.y * p.y);
    m[i] = 3.0e38f;
  }

#pragma unroll 2
  for (int b = 0; b < SLICELEN; b += 2) {
    float4 q0 = tile[b];
    float4 q1 = tile[b + 1];
#pragma unroll
    for (int i = 0; i < APT; ++i) {
      float t0 = fmaf(ny[i], q0.y, fmaf(nx[i], q0.x, q0.z));
      float t1 = fmaf(ny[i], q1.y, fmaf(nx[i], q1.x, q1.z));
      m[i] = fminf(fminf(t0, t1), m[i]);   // -> v_min3_f32
    }
  }

#pragma unroll
  for (int i = 0; i < APT; ++i) {
    int a = abase + i * BLK;
    if (a < NPTS) {
      float d = sqrtf(fmaxf(m[i] + p2[i], 0.f));
      // non-negative floats order-preserve as uint bit patterns; exact & deterministic
      atomicMin((unsigned int*)&minarr[Aset * NPTS + a], __float_as_uint(d));
    }
  }
}

// --------------------------------------------------------------- per-set sums
__global__ void k_reduce(const float2* __restrict__ pts,
                         const float* __restrict__ minarr,
                         float* acc, int* cnt) {
  __shared__ float sbuf[4];
  int set = blockIdx.x;
  float s = 0.f, c = 0.f;
  for (int i = threadIdx.x; i < NPTS; i += 256) {
    float2 p = pts[set * NPTS + i];
    if (p.x < 1.0e6f) { s += minarr[set * NPTS + i]; c += 1.f; }
  }
  s = block_reduce_sum(s, sbuf);
  __syncthreads();
  c = block_reduce_sum(c, sbuf);
  if (threadIdx.x == 0) { acc[1 + set] = s; cnt[set] = (int)c; }
}

// ---------------------------------------------------------------- final combine
__global__ void k_final(const float* __restrict__ acc, const int* __restrict__ cnt,
                        float* __restrict__ out) {
  // chamfer_b = -sum_pred/np + sum_gt/ng
  float ch0 = -acc[1] / fmaxf((float)cnt[0], 1.f) + acc[3] / fmaxf((float)cnt[2], 1.f);
  float ch1 = -acc[2] / fmaxf((float)cnt[1], 1.f) + acc[4] / fmaxf((float)cnt[3], 1.f);
  out[0] = acc[0];               // PIXEL_W * pixel_loss, PIXEL_W = 1
  out[1] = 0.5f * (ch0 + ch1);   // mean over the 2 batches
}

extern "C" void kernel_launch(void* const* d_in, const int* in_sizes, int n_in,
                              void* d_out, int out_size, void* d_ws, size_t ws_size,
                              hipStream_t stream) {
  const float* pred = (const float*)d_in[0];
  const float* gt   = (const float*)d_in[1];
  float* out = (float*)d_out;

  // ws layout: [0..255] scalars | 4*NPTS float2 points | 4*NPTS float mins
  float* acc = (float*)d_ws;               // acc[0]=pixel, acc[1..4]=per-set sums
  int*   cnt = (int*)d_ws + 8;             // cnt[0..3]
  float2* pts = (float2*)((char*)d_ws + 256);
  float* minarr = (float*)((char*)d_ws + 256 + sizeof(float2) * 4 * NPTS);

  k_pixel<<<1, 256, 0, stream>>>(pred, gt, acc);
  k_extract<<<dim3(EXCHUNKS, 4), 256, 0, stream>>>(pred, gt, pts, minarr);
  k_min<<<dim3(ABLOCKS, NSLICE, 4), BLK, 0, stream>>>(pts, minarr);
  k_reduce<<<4, 256, 0, stream>>>(pts, minarr, acc, cnt);
  k_final<<<1, 1, 0, stream>>>(acc, cnt, out);
}

// Round 3
// 87.888 us; speedup vs baseline: 3.0439x; 1.1094x over previous
//
#include <hip/hip_runtime.h>

#define HH 80
#define WW 80
#define IMG (HH * WW)            // 6400
#define NV ((HH - 1) * WW)       // 6320 vertical edge slots
#define NPTS (NV + HH * (WW - 1))// 12640 edge slots per image
#define NPIX (2 * IMG)           // 12800
#define QTR (NPTS / 4)           // 3160 slots per wave in k_prep
#define BIGF 1.0e10f
#define INVC 1.0e7f
#define EPSF 1e-8f

#define APT 8                    // A points per thread in k_min
#define BLK 128                  // k_min block (2 waves)
#define NSLICE 32
#define MAXSLICE ((((NPTS + NSLICE - 1) / NSLICE) + 1) & ~1) // 396
#define ABLOCKS ((NPTS + BLK * APT - 1) / (BLK * APT))       // 13

__device__ __forceinline__ float wave_reduce_sum(float v) {
#pragma unroll
  for (int o = 32; o > 0; o >>= 1) v += __shfl_down(v, o, 64);
  return v;
}

// --------------------------------------------------------------- k_prep
// One block per set (0: pred b0, 1: pred b1, 2: gt b0, 3: gt b1).
// Does: minarr init, pixel-loss partial, and order-preserving compaction of
// valid zero-crossing points via a two-pass per-wave scan (deterministic).
__global__ void __launch_bounds__(256) k_prep(
    const float* __restrict__ pred, const float* __restrict__ gt,
    float2* __restrict__ pts, float* __restrict__ minarr,
    int* __restrict__ cnt, float* __restrict__ pixpart) {
  int set = blockIdx.x;
  int tid = threadIdx.x, lane = tid & 63, wid = tid >> 6;
  const float* s = (set < 2 ? pred : gt) + (set & 1) * IMG;

  __shared__ int wcnt_s[4];
  __shared__ float wpix_s[4];
  __shared__ int wbase_s[4];

  // minarr init (atomicMin target)
  for (int i = tid; i < NPTS; i += 256) minarr[set * NPTS + i] = BIGF;

  // pixel-loss partial: this set's quarter of the 12800 flat pixels
  float ps = 0.f;
  for (int i = set * (NPIX / 4) + tid; i < (set + 1) * (NPIX / 4); i += 256)
    ps += fabsf(pred[i] - gt[i]);
  ps = wave_reduce_sum(ps);
  if (lane == 0) wpix_s[wid] = ps;

  // pass 1: count valid slots in this wave's quarter [wid*QTR, (wid+1)*QTR)
  int mycnt = 0;
  int wbeg = wid * QTR;
  for (int base = 0; base < QTR; base += 64) {
    int idx = wbeg + base + lane;
    bool valid = false;
    if (base + lane < QTR) {
      if (idx < NV) {
        int i = idx / WW, j = idx - i * WW;
        float v1 = s[i * WW + j], v2 = s[(i + 1) * WW + j];
        valid = (v1 == 0.f) | (v2 == 0.f) | (v1 * v2 < 0.f);
      } else {
        int t = idx - NV;
        int i = t / (WW - 1), j = t - i * (WW - 1);
        float h1 = s[i * WW + j], h2 = s[i * WW + j + 1];
        valid = (h1 == 0.f) | (h2 == 0.f) | (h1 * h2 < 0.f);
      }
    }
    mycnt += valid ? 1 : 0;
  }
  mycnt = (int)wave_reduce_sum((float)mycnt);
  if (lane == 0) wcnt_s[wid] = mycnt;
  __syncthreads();
  if (tid == 0) {
    int b = 0;
    for (int w = 0; w < 4; ++w) { int t = wcnt_s[w]; wbase_s[w] = b; b += t; }
    cnt[set] = b;
    pixpart[set] = wpix_s[0] + wpix_s[1] + wpix_s[2] + wpix_s[3];
  }
  __syncthreads();

  // pass 2: recompute and write compacted points (order-preserving, no atomics)
  int off = wbase_s[wid];
  for (int base = 0; base < QTR; base += 64) {
    int idx = wbeg + base + lane;
    float r = 0.f, c = 0.f;
    bool valid = false;
    if (base + lane < QTR) {
      if (idx < NV) {
        int i = idx / WW, j = idx - i * WW;
        float v1 = s[i * WW + j], v2 = s[(i + 1) * WW + j];
        c = (float)j;
        if (v1 == 0.f)      { r = (float)i;       valid = true; }
        else if (v2 == 0.f) { r = (float)i + 1.f; valid = true; }
        else {
          r = (float)i + fabsf(v1) / (fabsf(v1) + fabsf(v2) + EPSF);
          valid = (v1 * v2 < 0.f);
        }
      } else {
        int t = idx - NV;
        int i = t / (WW - 1), j = t - i * (WW - 1);
        float h1 = s[i * WW + j], h2 = s[i * WW + j + 1];
        r = (float)i;
        if (h1 == 0.f)      { c = (float)j;       valid = true; }
        else if (h2 == 0.f) { c = (float)j + 1.f; valid = true; }
        else {
          c = (float)j + fabsf(h1) / (fabsf(h1) + fabsf(h2) + EPSF);
          valid = (h1 * h2 < 0.f);
        }
      }
    }
    unsigned long long mask = __ballot(valid);
    int lpos = __popcll(mask & ((1ull << lane) - 1ull));
    if (valid) pts[set * NPTS + off + lpos] = make_float2(r, c);
    off += __popcll(mask);
  }
}

// --------------------------------------------------------------- k_min
// dir 0: A=0 B=2 | dir 1: A=2 B=0 | dir 2: A=1 B=3 | dir 3: A=3 B=1
// min over b of (q2 - 2px*qx - 2py*qy); + p2 and sqrt are monotone (sqrt in k_fin).
__global__ void __launch_bounds__(BLK) k_min(
    const float2* __restrict__ pts, float* __restrict__ minarr,
    const int* __restrict__ cnt) {
  int dir = blockIdx.z;
  int Aset = ((dir & 1) << 1) | (dir >> 1);
  int Bset = Aset ^ 2;
  int cntA = cnt[Aset], cntB = cnt[Bset];

  int abase0 = blockIdx.x * (BLK * APT);
  if (abase0 >= cntA) return;
  int slicelen = (((cntB + NSLICE - 1) / NSLICE) + 1) & ~1;
  int b0 = blockIdx.y * slicelen;
  if (b0 >= cntB) return;
  int n = min(slicelen, cntB - b0);
  int sn = (n + 1) & ~1;  // pad to even with a dummy far point

  __shared__ float4 tile[MAXSLICE];
  for (int i = threadIdx.x; i < sn; i += BLK) {
    float2 q = (i < n) ? pts[Bset * NPTS + b0 + i] : make_float2(INVC, INVC);
    tile[i] = make_float4(q.x, q.y, fmaf(q.x, q.x, q.y * q.y), 0.f);
  }
  __syncthreads();

  int abase = abase0 + threadIdx.x;
  float nx[APT], ny[APT], p2[APT], m[APT];
#pragma unroll
  for (int i = 0; i < APT; ++i) {
    int a = abase + i * BLK;
    float2 p = (a < cntA) ? pts[Aset * NPTS + a] : make_float2(0.f, 0.f);
    nx[i] = -2.f * p.x;
    ny[i] = -2.f * p.y;
    p2[i] = fmaf(p.x, p.x, p.y * p.y);
    m[i] = 3.0e38f;
  }

#pragma unroll 2
  for (int b = 0; b < sn; b += 2) {
    float4 q0 = tile[b];
    float4 q1 = tile[b + 1];
#pragma unroll
    for (int i = 0; i < APT; ++i) {
      float t0 = fmaf(ny[i], q0.y, fmaf(nx[i], q0.x, q0.z));
      float t1 = fmaf(ny[i], q1.y, fmaf(nx[i], q1.x, q1.z));
      m[i] = fminf(fminf(t0, t1), m[i]);   // -> v_min3_f32
    }
  }

#pragma unroll
  for (int i = 0; i < APT; ++i) {
    int a = abase + i * BLK;
    if (a < cntA) {
      float d2 = fmaxf(m[i] + p2[i], 0.f);
      // non-negative floats order as uint bit patterns; min is order-exact
      atomicMin((unsigned int*)&minarr[Aset * NPTS + a], __float_as_uint(d2));
    }
  }
}

// --------------------------------------------------------------- k_fin
__global__ void __launch_bounds__(256) k_fin(
    const float* __restrict__ minarr, const int* __restrict__ cnt,
    const float* __restrict__ pixpart, float* __restrict__ out) {
  __shared__ float sbuf[4];
  __shared__ float ssum[4];
  int tid = threadIdx.x, lane = tid & 63, wid = tid >> 6;
  for (int set = 0; set < 4; ++set) {
    int n = cnt[set];
    float s = 0.f;
    for (int i = tid; i < n; i += 256) s += sqrtf(minarr[set * NPTS + i]);
    s = wave_reduce_sum(s);
    if (lane == 0) sbuf[wid] = s;
    __syncthreads();
    if (tid == 0) ssum[set] = sbuf[0] + sbuf[1] + sbuf[2] + sbuf[3];
    __syncthreads();
  }
  if (tid == 0) {
    float n0 = fmaxf((float)cnt[0], 1.f), n1 = fmaxf((float)cnt[1], 1.f);
    float n2 = fmaxf((float)cnt[2], 1.f), n3 = fmaxf((float)cnt[3], 1.f);
    float ch0 = -ssum[0] / n0 + ssum[2] / n2;
    float ch1 = -ssum[1] / n1 + ssum[3] / n3;
    out[0] = (pixpart[0] + pixpart[1] + pixpart[2] + pixpart[3]) / (float)NPIX;
    out[1] = 0.5f * (ch0 + ch1);
  }
}

extern "C" void kernel_launch(void* const* d_in, const int* in_sizes, int n_in,
                              void* d_out, int out_size, void* d_ws, size_t ws_size,
                              hipStream_t stream) {
  const float* pred = (const float*)d_in[0];
  const float* gt   = (const float*)d_in[1];
  float* out = (float*)d_out;

  // ws layout: 256B scalars | 4*NPTS float2 pts | 4*NPTS float mins
  int*   cnt     = (int*)d_ws;                  // [0..3]
  float* pixpart = (float*)d_ws + 4;            // [0..3]
  float2* pts    = (float2*)((char*)d_ws + 256);
  float* minarr  = (float*)((char*)d_ws + 256 + sizeof(float2) * 4 * NPTS);

  k_prep<<<4, 256, 0, stream>>>(pred, gt, pts, minarr, cnt, pixpart);
  k_min<<<dim3(ABLOCKS, NSLICE, 4), BLK, 0, stream>>>(pts, minarr, cnt);
  k_fin<<<1, 256, 0, stream>>>(minarr, cnt, pixpart, out);
}

// Round 4
// 40.496 us; speedup vs baseline: 6.6063x; 2.1703x over previous
//
#include <hip/hip_runtime.h>

#define HH 80
#define WW 80
#define IMG (HH * WW)             // 6400
#define NV ((HH - 1) * WW)        // 6320 vertical edge slots
#define NPTS (NV + HH * (WW - 1)) // 12640 edge slots per image
#define NPIX (2 * IMG)            // 12800
#define BIGF 1.0e10f
#define INVC 1.0e7f
#define EPSF 1e-8f
#define QSCALE 131072.0f          // 2^17 fixed-point scale for distance sums

#define PBLK 1024                 // k_prep block (16 waves)
#define PWAVES (PBLK / 64)
#define QTR (NPTS / PWAVES)       // 790 slots per wave (exact)

#define BLK 256                   // k_min block (4 waves)
#define APT 4                     // A points per thread
#define ACHUNK (BLK * APT)        // 1024
#define ABLOCKS ((NPTS + ACHUNK - 1) / ACHUNK) // 13 (worst case, runtime early-exit)
#define NSLICE 16
#define MAXSLICE ((((NPTS + NSLICE - 1) / NSLICE) + 1) & ~1) // 790

__device__ __forceinline__ float wave_reduce_f(float v) {
#pragma unroll
  for (int o = 32; o > 0; o >>= 1) v += __shfl_down(v, o, 64);
  return v;
}
__device__ __forceinline__ long long wave_reduce_ll(long long v) {
#pragma unroll
  for (int o = 32; o > 0; o >>= 1) {
    int2 p = *(int2*)&v;
    p.x = __shfl_down(p.x, o, 64);
    p.y = __shfl_down(p.y, o, 64);
    v += *(long long*)&p;
  }
  return v;
}

// --------------------------------------------------------------- k_prep
// One block (1024 thr) per set. Deterministic two-pass wave-scan compaction,
// minarr init, pixel-loss partial, and zeroing of k_fin's accumulators.
__global__ void __launch_bounds__(PBLK) k_prep(
    const float* __restrict__ pred, const float* __restrict__ gt,
    float2* __restrict__ pts, float* __restrict__ minarr,
    int* __restrict__ cnt, float* __restrict__ pixpart,
    unsigned long long* __restrict__ sum_i, unsigned int* __restrict__ ticket) {
  int set = blockIdx.x;
  int tid = threadIdx.x, lane = tid & 63, wid = tid >> 6;
  const float* s = (set < 2 ? pred : gt) + (set & 1) * IMG;

  __shared__ int wcnt_s[PWAVES];
  __shared__ float wpix_s[PWAVES];
  __shared__ int wbase_s[PWAVES];

  // zero k_fin accumulators (safe: consumed only after kernel boundary)
  if (set == 0 && tid < 4) sum_i[tid] = 0ull;
  if (set == 0 && tid == 4) *ticket = 0u;

  // minarr init (atomicMin target)
  for (int i = tid; i < NPTS; i += PBLK) minarr[set * NPTS + i] = BIGF;

  // pixel-loss partial: this set's quarter of the flat pixel array (fixed order)
  float ps = 0.f;
  for (int i = set * (NPIX / 4) + tid; i < (set + 1) * (NPIX / 4); i += PBLK)
    ps += fabsf(pred[i] - gt[i]);
  ps = wave_reduce_f(ps);
  if (lane == 0) wpix_s[wid] = ps;

  // pass 1: count valid slots in this wave's range [wid*QTR, (wid+1)*QTR)
  int mycnt = 0;
  int wbeg = wid * QTR;
  for (int base = 0; base < QTR; base += 64) {
    int idx = wbeg + base + lane;
    bool valid = false;
    if (base + lane < QTR) {
      if (idx < NV) {
        int i = idx / WW, j = idx - i * WW;
        float v1 = s[i * WW + j], v2 = s[(i + 1) * WW + j];
        valid = (v1 == 0.f) | (v2 == 0.f) | (v1 * v2 < 0.f);
      } else {
        int t = idx - NV;
        int i = t / (WW - 1), j = t - i * (WW - 1);
        float h1 = s[i * WW + j], h2 = s[i * WW + j + 1];
        valid = (h1 == 0.f) | (h2 == 0.f) | (h1 * h2 < 0.f);
      }
    }
    mycnt += valid ? 1 : 0;
  }
  unsigned long long m0 = __ballot(true); (void)m0;
  mycnt = (int)wave_reduce_f((float)mycnt);
  if (lane == 0) wcnt_s[wid] = mycnt;
  __syncthreads();
  if (tid == 0) {
    int b = 0;
    float px = 0.f;
    for (int w = 0; w < PWAVES; ++w) {
      wbase_s[w] = b; b += wcnt_s[w];
      px += wpix_s[w];
    }
    cnt[set] = b;
    pixpart[set] = px;
  }
  __syncthreads();

  // pass 2: recompute and write compacted points (order-preserving, no atomics)
  int off = wbase_s[wid];
  for (int base = 0; base < QTR; base += 64) {
    int idx = wbeg + base + lane;
    float r = 0.f, c = 0.f;
    bool valid = false;
    if (base + lane < QTR) {
      if (idx < NV) {
        int i = idx / WW, j = idx - i * WW;
        float v1 = s[i * WW + j], v2 = s[(i + 1) * WW + j];
        c = (float)j;
        if (v1 == 0.f)      { r = (float)i;       valid = true; }
        else if (v2 == 0.f) { r = (float)i + 1.f; valid = true; }
        else {
          r = (float)i + fabsf(v1) / (fabsf(v1) + fabsf(v2) + EPSF);
          valid = (v1 * v2 < 0.f);
        }
      } else {
        int t = idx - NV;
        int i = t / (WW - 1), j = t - i * (WW - 1);
        float h1 = s[i * WW + j], h2 = s[i * WW + j + 1];
        r = (float)i;
        if (h1 == 0.f)      { c = (float)j;       valid = true; }
        else if (h2 == 0.f) { c = (float)j + 1.f; valid = true; }
        else {
          c = (float)j + fabsf(h1) / (fabsf(h1) + fabsf(h2) + EPSF);
          valid = (h1 * h2 < 0.f);
        }
      }
    }
    unsigned long long mask = __ballot(valid);
    int lpos = __popcll(mask & ((1ull << lane) - 1ull));
    if (valid) pts[set * NPTS + off + lpos] = make_float2(r, c);
    off += __popcll(mask);
  }
}

// --------------------------------------------------------------- k_min
// dir 0: A=0 B=2 | dir 1: A=2 B=0 | dir 2: A=1 B=3 | dir 3: A=3 B=1
// min over b of (q2 - 2px*qx - 2py*qy); + p2 and sqrt are monotone (sqrt in k_fin).
__global__ void __launch_bounds__(BLK) k_min(
    const float2* __restrict__ pts, float* __restrict__ minarr,
    const int* __restrict__ cnt) {
  int dir = blockIdx.z;
  int Aset = ((dir & 1) << 1) | (dir >> 1);
  int Bset = Aset ^ 2;
  int cntA = cnt[Aset], cntB = cnt[Bset];

  int abase0 = blockIdx.x * ACHUNK;
  if (abase0 >= cntA) return;
  int slicelen = (((cntB + NSLICE - 1) / NSLICE) + 1) & ~1;
  int b0 = blockIdx.y * slicelen;
  if (b0 >= cntB) return;
  int n = min(slicelen, cntB - b0);
  int sn = (n + 1) & ~1;  // pad to even with a dummy far point

  __shared__ float4 tile[MAXSLICE];
  for (int i = threadIdx.x; i < sn; i += BLK) {
    float2 q = (i < n) ? pts[Bset * NPTS + b0 + i] : make_float2(INVC, INVC);
    tile[i] = make_float4(q.x, q.y, fmaf(q.x, q.x, q.y * q.y), 0.f);
  }
  __syncthreads();

  int abase = abase0 + threadIdx.x;
  float nx[APT], ny[APT], p2[APT], m[APT];
#pragma unroll
  for (int i = 0; i < APT; ++i) {
    int a = abase + i * BLK;
    float2 p = (a < cntA) ? pts[Aset * NPTS + a] : make_float2(0.f, 0.f);
    nx[i] = -2.f * p.x;
    ny[i] = -2.f * p.y;
    p2[i] = fmaf(p.x, p.x, p.y * p.y);
    m[i] = 3.0e38f;
  }

#pragma unroll 2
  for (int b = 0; b < sn; b += 2) {
    float4 q0 = tile[b];
    float4 q1 = tile[b + 1];
#pragma unroll
    for (int i = 0; i < APT; ++i) {
      float t0 = fmaf(ny[i], q0.y, fmaf(nx[i], q0.x, q0.z));
      float t1 = fmaf(ny[i], q1.y, fmaf(nx[i], q1.x, q1.z));
      m[i] = fminf(fminf(t0, t1), m[i]);   // -> v_min3_f32
    }
  }

#pragma unroll
  for (int i = 0; i < APT; ++i) {
    int a = abase + i * BLK;
    if (a < cntA) {
      float d2 = fmaxf(m[i] + p2[i], 0.f);
      // non-negative floats order as uint bit patterns; min is order-exact
      atomicMin((unsigned int*)&minarr[Aset * NPTS + a], __float_as_uint(d2));
    }
  }
}

// --------------------------------------------------------------- k_fin
// 16 blocks (4 per set): exact int64 partial sums of round(sqrt(d2)*2^17),
// device-scope atomicAdd (order-independent, bit-exact). Last block (ticket)
// combines and writes the two outputs.
__global__ void __launch_bounds__(256) k_fin(
    const float* __restrict__ minarr, const int* __restrict__ cnt,
    const float* __restrict__ pixpart, unsigned long long* __restrict__ sum_i,
    unsigned int* __restrict__ ticket, float* __restrict__ out) {
  int set = blockIdx.x >> 2, q = blockIdx.x & 3;
  int tid = threadIdx.x, lane = tid & 63;
  int n = cnt[set];

  long long ls = 0;
  for (int i = q * 256 + tid; i < n; i += 1024) {
    float d = sqrtf(minarr[set * NPTS + i]);
    ls += (long long)(d * QSCALE + 0.5f);
  }
  ls = wave_reduce_ll(ls);
  if (lane == 0) atomicAdd(&sum_i[set], (unsigned long long)ls);
  __syncthreads();

  if (tid == 0) {
    __threadfence();
    unsigned int t = atomicAdd(ticket, 1u);
    if (t == 15u) {  // all 16 blocks' adds complete (device-scope atomics)
      float ss[4];
      for (int k = 0; k < 4; ++k)
        ss[k] = (float)((long long)atomicAdd(&sum_i[k], 0ull)) * (1.0f / QSCALE);
      float n0 = fmaxf((float)cnt[0], 1.f), n1 = fmaxf((float)cnt[1], 1.f);
      float n2 = fmaxf((float)cnt[2], 1.f), n3 = fmaxf((float)cnt[3], 1.f);
      float ch0 = -ss[0] / n0 + ss[2] / n2;
      float ch1 = -ss[1] / n1 + ss[3] / n3;
      out[0] = (pixpart[0] + pixpart[1] + pixpart[2] + pixpart[3]) / (float)NPIX;
      out[1] = 0.5f * (ch0 + ch1);
    }
  }
}

extern "C" void kernel_launch(void* const* d_in, const int* in_sizes, int n_in,
                              void* d_out, int out_size, void* d_ws, size_t ws_size,
                              hipStream_t stream) {
  const float* pred = (const float*)d_in[0];
  const float* gt   = (const float*)d_in[1];
  float* out = (float*)d_out;

  // ws layout: scalars (256 B) | 4*NPTS float2 pts | 4*NPTS float mins
  int*   cnt     = (int*)d_ws;                              // [0..3]
  float* pixpart = (float*)d_ws + 4;                        // [4..7]
  unsigned long long* sum_i = (unsigned long long*)((char*)d_ws + 32); // [0..3]
  unsigned int* ticket = (unsigned int*)((char*)d_ws + 64);
  float2* pts    = (float2*)((char*)d_ws + 256);
  float* minarr  = (float*)((char*)d_ws + 256 + sizeof(float2) * 4 * NPTS);

  k_prep<<<4, PBLK, 0, stream>>>(pred, gt, pts, minarr, cnt, pixpart, sum_i, ticket);
  k_min<<<dim3(ABLOCKS, NSLICE, 4), BLK, 0, stream>>>(pts, minarr, cnt);
  k_fin<<<16, 256, 0, stream>>>(minarr, cnt, pixpart, sum_i, ticket, out);
}